// Round 1
// baseline (438.355 us; speedup 1.0000x reference)
//
#include <hip/hip_runtime.h>
#include <hip/hip_bf16.h>

// GridAttention: B=2, C=64, H=W=160, INTERVAL=8, HEADS=4, d=16
// Shuffled: Bp=128, h=w=20, N=400.
// Token-major scratch layout: T[bp][n][c] with c = head*16+dd contiguous (64 floats).

#define N_TOK 400
#define BP 128
#define CH 64

// ---------------- K1: positional bias MLP -> bias[4][400][400] ----------------
__global__ __launch_bounds__(256) void k_bias(
    const float* __restrict__ W1, const float* __restrict__ B1,
    const float* __restrict__ W2, const float* __restrict__ B2,
    float* __restrict__ bias)
{
    int idx = blockIdx.x * 256 + threadIdx.x;
    if (idx >= 160000) return;
    int n = idx / 400, m = idx % 400;
    float r0 = (float)(n / 20 - m / 20) / 19.0f;
    float r1 = (float)(n % 20 - m % 20) / 19.0f;
    float o0 = B2[0], o1 = B2[1], o2 = B2[2], o3 = B2[3];
#pragma unroll
    for (int k = 0; k < 16; ++k) {
        float h = r0 * W1[k] + r1 * W1[16 + k] + B1[k];
        h = fmaxf(h, 0.0f);
        o0 += h * W2[k * 4 + 0];
        o1 += h * W2[k * 4 + 1];
        o2 += h * W2[k * 4 + 2];
        o3 += h * W2[k * 4 + 3];
    }
    bias[idx] = o0;
    bias[160000 + idx] = o1;
    bias[320000 + idx] = o2;
    bias[480000 + idx] = o3;
}

// ---------------- K2: qkv + grid conv1x1, fused with grid_shuffle ----------------
// One block per (b, H0) row of the original image. Stages x[b][:][H0][:] into LDS
// transposed to [p=W0][c], then each thread (one output channel of 192 qkv + 64 grid)
// does 160 dot-64s with its weight row held in VGPRs (LDS reads are broadcasts).
__global__ __launch_bounds__(256) void k_qkvgrid(
    const float* __restrict__ x,
    const float* __restrict__ qkv_w, const float* __restrict__ qkv_b,
    const float* __restrict__ grid_w, const float* __restrict__ grid_b,
    float* __restrict__ Qb, float* __restrict__ Kb,
    float* __restrict__ Vb, float* __restrict__ XGb)
{
    __shared__ __align__(16) float xl[160 * 68];  // pad 64->68 (keeps 16B align, breaks bank stride)
    int blk = blockIdx.x;
    int b = blk / 160, H0 = blk % 160;
    int tid = threadIdx.x;

    const float* xb = x + ((size_t)b * 64 * 160 + H0) * 160;  // x[b][0][H0][0], c-stride 25600
    for (int idx = tid; idx < 64 * 40; idx += 256) {
        int c = idx / 40, w4 = idx % 40;
        float4 v = *reinterpret_cast<const float4*>(xb + (size_t)c * 25600 + w4 * 4);
        int p = w4 * 4;
        xl[(p + 0) * 68 + c] = v.x;
        xl[(p + 1) * 68 + c] = v.y;
        xl[(p + 2) * 68 + c] = v.z;
        xl[(p + 3) * 68 + c] = v.w;
    }

    // per-thread weight row (64 floats in VGPRs)
    float4 wr[16];
    float bb;
    {
        const float* wrow;
        if (tid < 192) { wrow = qkv_w + (size_t)tid * 64; bb = qkv_b[tid]; }
        else           { wrow = grid_w + (size_t)(tid - 192) * 64; bb = grid_b[tid - 192]; }
#pragma unroll
        for (int i = 0; i < 16; ++i) wr[i] = *reinterpret_cast<const float4*>(wrow + 4 * i);
    }
    __syncthreads();

    int hh = H0 / 8, iI = H0 % 8;
    int group = tid >> 6;   // 0:Q 1:K 2:V 3:XG
    int cc = tid & 63;
    float* outbuf = (group == 0) ? Qb : (group == 1) ? Kb : (group == 2) ? Vb : XGb;

    for (int p = 0; p < 160; ++p) {
        const float* xp = &xl[p * 68];
        float acc = bb;
#pragma unroll
        for (int i = 0; i < 16; ++i) {
            float4 xv = *reinterpret_cast<const float4*>(xp + 4 * i);
            acc += wr[i].x * xv.x + wr[i].y * xv.y + wr[i].z * xv.z + wr[i].w * xv.w;
        }
        int ww = p >> 3, j = p & 7;
        int bp = b * 64 + iI * 8 + j;
        int n  = hh * 20 + ww;
        outbuf[((size_t)bp * 400 + n) * 64 + cc] = acc;
    }
}

// ---------------- K3: attention (one block per (bp, head)) ----------------
// K,V rows in LDS; one thread per query row; online softmax with deferred rescale.
__global__ __launch_bounds__(448) void k_attn(
    const float* __restrict__ Qb, const float* __restrict__ Kb,
    const float* __restrict__ Vb, const float* __restrict__ bias,
    float* __restrict__ Ob)
{
    __shared__ __align__(16) float Kl[400 * 16];
    __shared__ __align__(16) float Vl[400 * 16];
    int blk = blockIdx.x;
    int bp = blk >> 2, head = blk & 3;
    int tid = threadIdx.x;

    const float* Kg = Kb + (size_t)bp * 400 * 64 + head * 16;
    const float* Vg = Vb + (size_t)bp * 400 * 64 + head * 16;
    for (int idx = tid; idx < 1600; idx += 448) {
        int m = idx >> 2, d4 = idx & 3;
        *reinterpret_cast<float4*>(&Kl[m * 16 + d4 * 4]) =
            *reinterpret_cast<const float4*>(Kg + (size_t)m * 64 + d4 * 4);
        *reinterpret_cast<float4*>(&Vl[m * 16 + d4 * 4]) =
            *reinterpret_cast<const float4*>(Vg + (size_t)m * 64 + d4 * 4);
    }

    int n = tid;
    float4 q0, q1, q2, q3;
    if (n < 400) {
        const float* qg = Qb + ((size_t)bp * 400 + n) * 64 + head * 16;
        const float sc = 0.25f;
        q0 = *reinterpret_cast<const float4*>(qg + 0);
        q1 = *reinterpret_cast<const float4*>(qg + 4);
        q2 = *reinterpret_cast<const float4*>(qg + 8);
        q3 = *reinterpret_cast<const float4*>(qg + 12);
        q0.x *= sc; q0.y *= sc; q0.z *= sc; q0.w *= sc;
        q1.x *= sc; q1.y *= sc; q1.z *= sc; q1.w *= sc;
        q2.x *= sc; q2.y *= sc; q2.z *= sc; q2.w *= sc;
        q3.x *= sc; q3.y *= sc; q3.z *= sc; q3.w *= sc;
    }
    __syncthreads();
    if (n >= 400) return;

    const float* brow = bias + (size_t)head * 160000 + (size_t)n * 400;
    float mrun = -1e30f, lrun = 0.0f;
    float4 a0 = {0, 0, 0, 0}, a1 = {0, 0, 0, 0}, a2 = {0, 0, 0, 0}, a3 = {0, 0, 0, 0};

    for (int m0 = 0; m0 < 400; m0 += 4) {
        float4 b4 = *reinterpret_cast<const float4*>(brow + m0);
#pragma unroll
        for (int k = 0; k < 4; ++k) {
            int m = m0 + k;
            const float4* kp = reinterpret_cast<const float4*>(&Kl[m * 16]);
            float4 k0 = kp[0], k1 = kp[1], k2 = kp[2], k3 = kp[3];
            float s = (k == 0) ? b4.x : (k == 1) ? b4.y : (k == 2) ? b4.z : b4.w;
            s += q0.x * k0.x + q0.y * k0.y + q0.z * k0.z + q0.w * k0.w;
            s += q1.x * k1.x + q1.y * k1.y + q1.z * k1.z + q1.w * k1.w;
            s += q2.x * k2.x + q2.y * k2.y + q2.z * k2.z + q2.w * k2.w;
            s += q3.x * k3.x + q3.y * k3.y + q3.z * k3.z + q3.w * k3.w;
            float p;
            if (s > mrun) {
                float r = __expf(mrun - s);
                lrun *= r;
                a0.x *= r; a0.y *= r; a0.z *= r; a0.w *= r;
                a1.x *= r; a1.y *= r; a1.z *= r; a1.w *= r;
                a2.x *= r; a2.y *= r; a2.z *= r; a2.w *= r;
                a3.x *= r; a3.y *= r; a3.z *= r; a3.w *= r;
                mrun = s;
                p = 1.0f;
            } else {
                p = __expf(s - mrun);
            }
            lrun += p;
            const float4* vp = reinterpret_cast<const float4*>(&Vl[m * 16]);
            float4 v0 = vp[0], v1 = vp[1], v2 = vp[2], v3 = vp[3];
            a0.x += p * v0.x; a0.y += p * v0.y; a0.z += p * v0.z; a0.w += p * v0.w;
            a1.x += p * v1.x; a1.y += p * v1.y; a1.z += p * v1.z; a1.w += p * v1.w;
            a2.x += p * v2.x; a2.y += p * v2.y; a2.z += p * v2.z; a2.w += p * v2.w;
            a3.x += p * v3.x; a3.y += p * v3.y; a3.z += p * v3.z; a3.w += p * v3.w;
        }
    }
    float inv = 1.0f / lrun;
    float* og = Ob + ((size_t)bp * 400 + n) * 64 + head * 16;
    a0.x *= inv; a0.y *= inv; a0.z *= inv; a0.w *= inv;
    a1.x *= inv; a1.y *= inv; a1.z *= inv; a1.w *= inv;
    a2.x *= inv; a2.y *= inv; a2.z *= inv; a2.w *= inv;
    a3.x *= inv; a3.y *= inv; a3.z *= inv; a3.w *= inv;
    *reinterpret_cast<float4*>(og + 0)  = a0;
    *reinterpret_cast<float4*>(og + 4)  = a1;
    *reinterpret_cast<float4*>(og + 8)  = a2;
    *reinterpret_cast<float4*>(og + 12) = a3;
}

// ---------------- K4: token-wise 64x64 conv1x1 (token-major -> token-major) ----------------
__global__ __launch_bounds__(256) void k_proj(
    const float* __restrict__ In, const float* __restrict__ W,
    const float* __restrict__ Bv, float* __restrict__ Out)
{
    __shared__ __align__(16) float tl[64 * 64];
    size_t t0 = (size_t)blockIdx.x * 64;
    int tid = threadIdx.x;

    const float4* ig = reinterpret_cast<const float4*>(In + t0 * 64);
    float4* tlv = reinterpret_cast<float4*>(tl);
#pragma unroll
    for (int k = 0; k < 4; ++k) tlv[tid + k * 256] = ig[tid + k * 256];

    int co = tid & 63, grp = tid >> 6;
    float4 wr[16];
#pragma unroll
    for (int i = 0; i < 16; ++i) wr[i] = *reinterpret_cast<const float4*>(W + (size_t)co * 64 + 4 * i);
    float bb = Bv[co];
    __syncthreads();

    for (int tt = 0; tt < 16; ++tt) {
        int t = grp * 16 + tt;
        const float4* xp = reinterpret_cast<const float4*>(&tl[t * 64]);
        float acc = bb;
#pragma unroll
        for (int i = 0; i < 16; ++i) {
            float4 xv = xp[i];
            acc += wr[i].x * xv.x + wr[i].y * xv.y + wr[i].z * xv.z + wr[i].w * xv.w;
        }
        Out[(t0 + t) * 64 + co] = acc;
    }
}

// ---------------- K5: grid_unshuffle (token-major -> [B][C][160][160]) ----------------
__global__ __launch_bounds__(256) void k_unshuffle(
    const float* __restrict__ In, float* __restrict__ out)
{
    __shared__ __align__(16) float il[160 * 64];
    int blk = blockIdx.x;
    int b = blk / 160, rem = blk % 160, iI = rem / 20, hh = rem % 20;
    int tid = threadIdx.x;

    for (int idx = tid; idx < 2560; idx += 256) {
        int j = idx / 320, r2 = idx % 320, ww = r2 / 16, c4 = r2 % 16;
        int bp = b * 64 + iI * 8 + j;
        int n  = hh * 20 + ww;
        float4 v = reinterpret_cast<const float4*>(In + ((size_t)bp * 400 + n) * 64)[c4];
        reinterpret_cast<float4*>(&il[(ww * 8 + j) * 64])[c4] = v;
    }
    __syncthreads();

    int c = tid >> 2, q = tid & 3;
    int H0 = hh * 8 + iI;
    float* og = out + ((size_t)(b * 64 + c) * 160 + H0) * 160;
#pragma unroll
    for (int k = 0; k < 10; ++k) {
        int f = q + 4 * k;
        float4 v;
        v.x = il[(4 * f + 0) * 64 + c];
        v.y = il[(4 * f + 1) * 64 + c];
        v.z = il[(4 * f + 2) * 64 + c];
        v.w = il[(4 * f + 3) * 64 + c];
        reinterpret_cast<float4*>(og)[f] = v;
    }
}

extern "C" void kernel_launch(void* const* d_in, const int* in_sizes, int n_in,
                              void* d_out, int out_size, void* d_ws, size_t ws_size,
                              hipStream_t stream)
{
    const float* x      = (const float*)d_in[0];
    const float* qkv_w  = (const float*)d_in[1];
    const float* qkv_b  = (const float*)d_in[2];
    const float* grid_w = (const float*)d_in[3];
    const float* grid_b = (const float*)d_in[4];
    const float* pw1    = (const float*)d_in[5];
    const float* pb1    = (const float*)d_in[6];
    const float* pw2    = (const float*)d_in[7];
    const float* pb2    = (const float*)d_in[8];
    const float* p1w    = (const float*)d_in[9];
    const float* p1b    = (const float*)d_in[10];
    const float* p2w    = (const float*)d_in[11];
    const float* p2b    = (const float*)d_in[12];

    float* ws = (float*)d_ws;
    const size_t TOK = (size_t)BP * N_TOK * CH;  // 3,276,800 floats
    float* XG   = ws;
    float* Qb   = ws + TOK;
    float* Kb   = ws + 2 * TOK;
    float* Vb   = ws + 3 * TOK;
    float* O1   = ws + 4 * TOK;
    float* bias = ws + 5 * TOK;  // 640,000 floats
    float* out  = (float*)d_out;

    k_bias<<<625, 256, 0, stream>>>(pw1, pb1, pw2, pb2, bias);
    k_qkvgrid<<<320, 256, 0, stream>>>(x, qkv_w, qkv_b, grid_w, grid_b, Qb, Kb, Vb, XG);
    // mask_attn #1: q=x_grid, k=K, v=V  -> O1, then proj1 -> P1 (reuse V buffer)
    k_attn<<<512, 448, 0, stream>>>(XG, Kb, Vb, bias, O1);
    k_proj<<<800, 256, 0, stream>>>(O1, p1w, p1b, Vb);
    // mask_attn #2: q=Q, k=x_grid, v=P1 -> O2 (reuse K buffer), then proj2 -> O3 (reuse O1)
    k_attn<<<512, 448, 0, stream>>>(Qb, XG, Vb, bias, Kb);
    k_proj<<<800, 256, 0, stream>>>(Kb, p2w, p2b, O1);
    k_unshuffle<<<320, 256, 0, stream>>>(O1, out);
}

// Round 2
// 227.244 us; speedup vs baseline: 1.9290x; 1.9290x over previous
//
#include <hip/hip_runtime.h>
#include <hip/hip_bf16.h>

// GridAttention: B=2, C=64, H=W=160, INTERVAL=8, HEADS=4, d=16
// Bp=128, h=w=20, N=400 (padded to 416). Token-major [bp][n][c], c=head*16+dd.

#define N_TOK 400
#define NP    416
#define BP    128
#define CH    64

typedef short bf16x8 __attribute__((ext_vector_type(8)));
typedef float f32x16 __attribute__((ext_vector_type(16)));

__device__ inline ushort f2bf(float f) {
    __hip_bfloat16 h = __float2bfloat16(f);
    return *reinterpret_cast<ushort*>(&h);
}
__device__ inline uint pk2(float a, float b) {
    return (uint)f2bf(a) | ((uint)f2bf(b) << 16);
}
__device__ inline bf16x8 ld16(const ushort* p) {
    union { uint4 q; bf16x8 v; } u;
    u.q = *reinterpret_cast<const uint4*>(p);
    return u.v;
}

// ---------------- K0: zero the 16 pad rows of the 5 bf16 staging buffers ----------------
__global__ __launch_bounds__(256) void k_zeropad(
    uint* a, uint* b, uint* c, uint* d, uint* e)
{
    int i = blockIdx.x * 256 + threadIdx.x;          // 65536 = 128*16*32
    int bp = i >> 9, rem = i & 511, r = rem >> 5, c2 = rem & 31;
    size_t off = ((size_t)(bp * NP + N_TOK + r)) * 32 + c2;
    a[off] = 0; b[off] = 0; c[off] = 0; d[off] = 0; e[off] = 0;
}

// ---------------- K1: positional bias MLP -> biasT[4][416(m)][400(n)] ----------------
__global__ __launch_bounds__(256) void k_biasT(
    const float* __restrict__ W1, const float* __restrict__ B1,
    const float* __restrict__ W2, const float* __restrict__ B2,
    float* __restrict__ biasT)
{
    int idx = blockIdx.x * 256 + threadIdx.x;
    if (idx >= 160000) return;
    int m = idx / 400, n = idx % 400;
    float r0 = (float)(n / 20 - m / 20) / 19.0f;
    float r1 = (float)(n % 20 - m % 20) / 19.0f;
    float o0 = B2[0], o1 = B2[1], o2 = B2[2], o3 = B2[3];
#pragma unroll
    for (int k = 0; k < 16; ++k) {
        float h = r0 * W1[k] + r1 * W1[16 + k] + B1[k];
        h = fmaxf(h, 0.0f);
        o0 += h * W2[k * 4 + 0];
        o1 += h * W2[k * 4 + 1];
        o2 += h * W2[k * 4 + 2];
        o3 += h * W2[k * 4 + 3];
    }
    size_t base = (size_t)m * 400 + n;
    biasT[base] = o0;
    biasT[166400 + base] = o1;
    biasT[2 * 166400 + base] = o2;
    biasT[3 * 166400 + base] = o3;
}

// ---------------- K2: qkv + grid conv1x1 fused with grid_shuffle -> bf16 ----------------
__global__ __launch_bounds__(256) void k_qkvgrid(
    const float* __restrict__ x,
    const float* __restrict__ qkv_w, const float* __restrict__ qkv_b,
    const float* __restrict__ grid_w, const float* __restrict__ grid_b,
    ushort* __restrict__ Qb, ushort* __restrict__ Kb,
    ushort* __restrict__ Vb, ushort* __restrict__ XGb)
{
    __shared__ __align__(16) float xl[160 * 68];
    int blk = blockIdx.x;
    int b = blk / 160, H0 = blk % 160;
    int tid = threadIdx.x;

    const float* xb = x + ((size_t)b * 64 * 160 + H0) * 160;
    for (int idx = tid; idx < 64 * 40; idx += 256) {
        int c = idx / 40, w4 = idx % 40;
        float4 v = *reinterpret_cast<const float4*>(xb + (size_t)c * 25600 + w4 * 4);
        int p = w4 * 4;
        xl[(p + 0) * 68 + c] = v.x;
        xl[(p + 1) * 68 + c] = v.y;
        xl[(p + 2) * 68 + c] = v.z;
        xl[(p + 3) * 68 + c] = v.w;
    }

    float4 wr[16];
    float bb;
    {
        const float* wrow;
        if (tid < 192) { wrow = qkv_w + (size_t)tid * 64; bb = qkv_b[tid]; }
        else           { wrow = grid_w + (size_t)(tid - 192) * 64; bb = grid_b[tid - 192]; }
#pragma unroll
        for (int i = 0; i < 16; ++i) wr[i] = *reinterpret_cast<const float4*>(wrow + 4 * i);
    }
    __syncthreads();

    int hh = H0 / 8, iI = H0 % 8;
    int group = tid >> 6;
    int cc = tid & 63;
    ushort* outbuf = (group == 0) ? Qb : (group == 1) ? Kb : (group == 2) ? Vb : XGb;

    for (int p = 0; p < 160; ++p) {
        const float* xp = &xl[p * 68];
        float acc = bb;
#pragma unroll
        for (int i = 0; i < 16; ++i) {
            float4 xv = *reinterpret_cast<const float4*>(xp + 4 * i);
            acc += wr[i].x * xv.x + wr[i].y * xv.y + wr[i].z * xv.z + wr[i].w * xv.w;
        }
        int ww = p >> 3, j = p & 7;
        int bp = b * 64 + iI * 8 + j;
        int n  = hh * 20 + ww;
        outbuf[((size_t)bp * NP + n) * 64 + cc] = f2bf(acc);
    }
}

// ---------------- K3: MFMA attention. One block per (bp, head); 4 waves ----------------
// Swapped QK^T (S^T frag: q=lane&31, m in regs), direct exp (scores tiny),
// cvt_pk + v_permlane32_swap -> PV A-operand in-register, 32x32x16 PV.
__global__ __launch_bounds__(256) void k_attn_mfma(
    const ushort* __restrict__ Qg, const ushort* __restrict__ Kg,
    const ushort* __restrict__ Vg, const float* __restrict__ biasT,
    float* __restrict__ O, float scale)
{
    __shared__ ushort Ks[NP * 16];    // [m][d]  row stride 32B
    __shared__ ushort Vt[16 * 424];   // [d][m]  row stride 848B (bank-friendly)
    int blk = blockIdx.x;
    int bp = blk >> 2, h = blk & 3;
    int tid = threadIdx.x;

    const ushort* Ksrc = Kg + (size_t)bp * NP * 64 + h * 16;
    for (int i = tid; i < NP * 2; i += 256) {
        int row = i >> 1, half = i & 1;
        *reinterpret_cast<uint4*>(&Ks[row * 16 + half * 8]) =
            *reinterpret_cast<const uint4*>(&Ksrc[(size_t)row * 64 + half * 8]);
    }
    const ushort* Vsrc = Vg + (size_t)bp * NP * 64 + h * 16;
    {
        int c = tid & 15, r0 = tid >> 4;
        for (int row = r0; row < N_TOK; row += 16)
            Vt[c * 424 + row] = Vsrc[(size_t)row * 64 + c];
    }
    __syncthreads();

    int lane = tid & 63, w = tid >> 6;
    int l31 = lane & 31, hi = lane >> 5;
    const float* bh = biasT + (size_t)h * 166400;

    for (int qt = w; qt < 13; qt += 4) {
        int qbase = qt * 32;
        bf16x8 qf = ld16(&Qg[((size_t)bp * NP + qbase + l31) * 64 + h * 16 + hi * 8]);
        f32x16 acc = 0.0f;
        float lrun = 0.0f;

#pragma unroll
        for (int mt = 0; mt < 13; ++mt) {
            const int mbase = mt * 32;
            bf16x8 kf = ld16(&Ks[(mbase + l31) * 16 + hi * 8]);
            f32x16 zero = 0.0f;
            f32x16 sv = __builtin_amdgcn_mfma_f32_32x32x16_bf16(kf, qf, zero, 0, 0, 0);

            // bias: biasT row m = mbase + (r&3)+8*(r>>2)+4*hi, col n = qbase+l31
            const float* bptr = bh + (size_t)mbase * 400 + qbase + l31 + hi * 1600;
            const int nv = (mt == 12) ? 8 : 16;   // tail tile: m 400..415 masked out
            float p[16];
            float rs = 0.0f;
#pragma unroll
            for (int r = 0; r < 16; ++r) {
                if (r < nv) {
                    float b = bptr[((r & 3) + 8 * (r >> 2)) * 400];
                    p[r] = __expf(fmaf(sv[r], scale, b));
                    rs += p[r];
                }
            }
            lrun += rs;

            // chunk 0 (m mbase..mbase+15): pack + permlane swap -> A-frag
            {
                uint c0 = pk2(p[0], p[1]), c1 = pk2(p[2], p[3]);
                uint c2 = pk2(p[4], p[5]), c3 = pk2(p[6], p[7]);
                asm("v_permlane32_swap_b32 %0, %1" : "+v"(c0), "+v"(c2));
                asm("v_permlane32_swap_b32 %0, %1" : "+v"(c1), "+v"(c3));
                union { uint u[4]; bf16x8 v; } A;
                A.u[0] = c0; A.u[1] = c1; A.u[2] = c2; A.u[3] = c3;
                bf16x8 vf = ld16(&Vt[(lane & 15) * 424 + mbase + hi * 8]);
                acc = __builtin_amdgcn_mfma_f32_32x32x16_bf16(A.v, vf, acc, 0, 0, 0);
            }
            // chunk 1 (m mbase+16..mbase+31): skipped on tail tile (all masked)
            if (mt < 12) {
                uint c4 = pk2(p[8], p[9]),  c5 = pk2(p[10], p[11]);
                uint c6 = pk2(p[12], p[13]), c7 = pk2(p[14], p[15]);
                asm("v_permlane32_swap_b32 %0, %1" : "+v"(c4), "+v"(c6));
                asm("v_permlane32_swap_b32 %0, %1" : "+v"(c5), "+v"(c7));
                union { uint u[4]; bf16x8 v; } A;
                A.u[0] = c4; A.u[1] = c5; A.u[2] = c6; A.u[3] = c7;
                bf16x8 vf = ld16(&Vt[(lane & 15) * 424 + mbase + 16 + hi * 8]);
                acc = __builtin_amdgcn_mfma_f32_32x32x16_bf16(A.v, vf, acc, 0, 0, 0);
            }
        }

        // normalize + store. acc: row q = qbase+(r&3)+8*(r>>2)+4*hi, col d = lane&31 (<16 valid)
        float tot = lrun + __shfl_xor(lrun, 32);
        float inv = 1.0f / tot;
        int dd = l31;
#pragma unroll
        for (int r = 0; r < 16; ++r) {
            int moff = (r & 3) + 8 * (r >> 2) + 4 * hi;
            int q = qbase + moff;
            float iv = __shfl(inv, moff);
            if (dd < 16 && q < N_TOK)
                O[((size_t)bp * N_TOK + q) * 64 + h * 16 + dd] = acc[r] * iv;
        }
    }
}

// ---------------- K4a: 64x64 conv1x1, fp32 in -> fp32 out (contiguous 400-stride) ----------------
__global__ __launch_bounds__(256) void k_proj_f32(
    const float* __restrict__ In, const float* __restrict__ W,
    const float* __restrict__ Bv, float* __restrict__ Out)
{
    __shared__ __align__(16) float tl[64 * 64];
    size_t t0 = (size_t)blockIdx.x * 64;
    int tid = threadIdx.x;

    const float4* ig = reinterpret_cast<const float4*>(In + t0 * 64);
    float4* tlv = reinterpret_cast<float4*>(tl);
#pragma unroll
    for (int k = 0; k < 4; ++k) tlv[tid + k * 256] = ig[tid + k * 256];

    int co = tid & 63, grp = tid >> 6;
    float4 wr[16];
#pragma unroll
    for (int i = 0; i < 16; ++i) wr[i] = *reinterpret_cast<const float4*>(W + (size_t)co * 64 + 4 * i);
    float bb = Bv[co];
    __syncthreads();

    for (int tt = 0; tt < 16; ++tt) {
        int t = grp * 16 + tt;
        const float4* xp = reinterpret_cast<const float4*>(&tl[t * 64]);
        float acc = bb;
#pragma unroll
        for (int i = 0; i < 16; ++i) {
            float4 xv = xp[i];
            acc += wr[i].x * xv.x + wr[i].y * xv.y + wr[i].z * xv.z + wr[i].w * xv.w;
        }
        Out[(t0 + t) * 64 + co] = acc;
    }
}

// ---------------- K4b: 64x64 conv1x1, fp32 in -> bf16 out (padded 416-stride) ----------------
__global__ __launch_bounds__(256) void k_proj_bf16(
    const float* __restrict__ In, const float* __restrict__ W,
    const float* __restrict__ Bv, ushort* __restrict__ Out)
{
    __shared__ __align__(16) float tl[64 * 64];
    size_t t0 = (size_t)blockIdx.x * 64;
    int tid = threadIdx.x;

    const float4* ig = reinterpret_cast<const float4*>(In + t0 * 64);
    float4* tlv = reinterpret_cast<float4*>(tl);
#pragma unroll
    for (int k = 0; k < 4; ++k) tlv[tid + k * 256] = ig[tid + k * 256];

    int co = tid & 63, grp = tid >> 6;
    float4 wr[16];
#pragma unroll
    for (int i = 0; i < 16; ++i) wr[i] = *reinterpret_cast<const float4*>(W + (size_t)co * 64 + 4 * i);
    float bb = Bv[co];
    __syncthreads();

    for (int tt = 0; tt < 16; ++tt) {
        int t = grp * 16 + tt;
        const float4* xp = reinterpret_cast<const float4*>(&tl[t * 64]);
        float acc = bb;
#pragma unroll
        for (int i = 0; i < 16; ++i) {
            float4 xv = xp[i];
            acc += wr[i].x * xv.x + wr[i].y * xv.y + wr[i].z * xv.z + wr[i].w * xv.w;
        }
        size_t T = t0 + t;
        int bp = (int)(T / 400), n = (int)(T - (size_t)bp * 400);
        Out[((size_t)bp * NP + n) * 64 + co] = f2bf(acc);
    }
}

// ---------------- K5: grid_unshuffle (token-major fp32 -> [B][C][160][160]) ----------------
__global__ __launch_bounds__(256) void k_unshuffle(
    const float* __restrict__ In, float* __restrict__ out)
{
    __shared__ __align__(16) float il[160 * 64];
    int blk = blockIdx.x;
    int b = blk / 160, rem = blk % 160, iI = rem / 20, hh = rem % 20;
    int tid = threadIdx.x;

    for (int idx = tid; idx < 2560; idx += 256) {
        int j = idx / 320, r2 = idx % 320, ww = r2 / 16, c4 = r2 % 16;
        int bp = b * 64 + iI * 8 + j;
        int n  = hh * 20 + ww;
        float4 v = reinterpret_cast<const float4*>(In + ((size_t)bp * 400 + n) * 64)[c4];
        reinterpret_cast<float4*>(&il[(ww * 8 + j) * 64])[c4] = v;
    }
    __syncthreads();

    int c = tid >> 2, q = tid & 3;
    int H0 = hh * 8 + iI;
    float* og = out + ((size_t)(b * 64 + c) * 160 + H0) * 160;
#pragma unroll
    for (int k = 0; k < 10; ++k) {
        int f = q + 4 * k;
        float4 v;
        v.x = il[(4 * f + 0) * 64 + c];
        v.y = il[(4 * f + 1) * 64 + c];
        v.z = il[(4 * f + 2) * 64 + c];
        v.w = il[(4 * f + 3) * 64 + c];
        reinterpret_cast<float4*>(og)[f] = v;
    }
}

extern "C" void kernel_launch(void* const* d_in, const int* in_sizes, int n_in,
                              void* d_out, int out_size, void* d_ws, size_t ws_size,
                              hipStream_t stream)
{
    const float* x      = (const float*)d_in[0];
    const float* qkv_w  = (const float*)d_in[1];
    const float* qkv_b  = (const float*)d_in[2];
    const float* grid_w = (const float*)d_in[3];
    const float* grid_b = (const float*)d_in[4];
    const float* pw1    = (const float*)d_in[5];
    const float* pb1    = (const float*)d_in[6];
    const float* pw2    = (const float*)d_in[7];
    const float* pb2    = (const float*)d_in[8];
    const float* p1w    = (const float*)d_in[9];
    const float* p1b    = (const float*)d_in[10];
    const float* p2w    = (const float*)d_in[11];
    const float* p2b    = (const float*)d_in[12];

    // workspace layout (float units)
    float* ws = (float*)d_ws;
    const size_t BF   = (size_t)BP * NP * 64 / 2;  // 1,703,936 floats per bf16 buffer
    const size_t TOKF = (size_t)BP * N_TOK * 64;   // 3,276,800 floats per fp32 buffer
    float*  biasT = ws;                            // 666,624 (4*416*400 + slack)
    ushort* Qb  = (ushort*)(ws + 666624);
    ushort* Kb  = (ushort*)(ws + 666624 + 1 * BF);
    ushort* Vb  = (ushort*)(ws + 666624 + 2 * BF);
    ushort* XG  = (ushort*)(ws + 666624 + 3 * BF);
    ushort* P1  = (ushort*)(ws + 666624 + 4 * BF);
    float*  O1  = ws + 666624 + 5 * BF;
    float*  O2  = O1 + TOKF;
    float*  out = (float*)d_out;

    k_zeropad<<<256, 256, 0, stream>>>((uint*)Qb, (uint*)Kb, (uint*)Vb, (uint*)XG, (uint*)P1);
    k_biasT<<<625, 256, 0, stream>>>(pw1, pb1, pw2, pb2, biasT);
    k_qkvgrid<<<320, 256, 0, stream>>>(x, qkv_w, qkv_b, grid_w, grid_b, Qb, Kb, Vb, XG);
    // attn1: q=XG, k=Kb, v=Vb -> O1 ; proj1 -> P1 (bf16, padded)
    k_attn_mfma<<<512, 256, 0, stream>>>(XG, Kb, Vb, biasT, O1, 0.25f);
    k_proj_bf16<<<800, 256, 0, stream>>>(O1, p1w, p1b, P1);
    // attn2: q=Qb, k=XG, v=P1 -> O2 ; proj2 -> O1 (fp32)
    k_attn_mfma<<<512, 256, 0, stream>>>(Qb, XG, P1, biasT, O2, 0.25f);
    k_proj_f32<<<800, 256, 0, stream>>>(O2, p2w, p2b, O1);
    k_unshuffle<<<320, 256, 0, stream>>>(O1, out);
}

// Round 3
// 151.439 us; speedup vs baseline: 2.8946x; 1.5006x over previous
//
#include <hip/hip_runtime.h>
#include <hip/hip_bf16.h>

// GridAttention: B=2, C=64, H=W=160, INTERVAL=8, HEADS=4, d=16
// Bp=128, h=w=20, N=400 (padded to 416). Token-major [bp][n][c], c=head*16+dd.

#define N_TOK 400
#define NP    416
#define BP    128

typedef short bf16x8 __attribute__((ext_vector_type(8)));
typedef float f32x16 __attribute__((ext_vector_type(16)));

__device__ inline ushort f2bf(float f) {
    __hip_bfloat16 h = __float2bfloat16(f);
    return *reinterpret_cast<ushort*>(&h);
}
__device__ inline float bf2f(ushort u) {
    union { uint i; float f; } v; v.i = (uint)u << 16; return v.f;
}
__device__ inline uint pk2(float a, float b) {
    return (uint)f2bf(a) | ((uint)f2bf(b) << 16);
}
__device__ inline bf16x8 ld16(const ushort* p) {
    union { uint4 q; bf16x8 v; } u;
    u.q = *reinterpret_cast<const uint4*>(p);
    return u.v;
}

// ---------------- K0: weight prep -> bf16 ----------------
// Wc[256][64] = concat(qkv_w, grid_w); Bc[256] = concat(qkv_b, grid_b); Wp1/Wp2 bf16.
__global__ __launch_bounds__(256) void k_prepw(
    const float* __restrict__ qkv_w, const float* __restrict__ qkv_b,
    const float* __restrict__ grid_w, const float* __restrict__ grid_b,
    const float* __restrict__ p1w, const float* __restrict__ p2w,
    ushort* __restrict__ Wc, float* __restrict__ Bc,
    ushort* __restrict__ Wp1, ushort* __restrict__ Wp2)
{
    int t = blockIdx.x * 256 + threadIdx.x;
    if (t < 16384) {
        int oc = t >> 6, k = t & 63;
        float v = (oc < 192) ? qkv_w[oc * 64 + k] : grid_w[(oc - 192) * 64 + k];
        Wc[t] = f2bf(v);
    } else if (t < 16384 + 4096) {
        Wp1[t - 16384] = f2bf(p1w[t - 16384]);
    } else if (t < 16384 + 8192) {
        Wp2[t - 16384 - 4096] = f2bf(p2w[t - 16384 - 4096]);
    } else if (t < 16384 + 8192 + 256) {
        int oc = t - 16384 - 8192;
        Bc[oc] = (oc < 192) ? qkv_b[oc] : grid_b[oc - 192];
    }
}

// ---------------- K1: positional bias MLP -> biasT[4][416(m)][400(n)] bf16 ----------------
__global__ __launch_bounds__(256) void k_biasT(
    const float* __restrict__ W1, const float* __restrict__ B1,
    const float* __restrict__ W2, const float* __restrict__ B2,
    ushort* __restrict__ biasT)
{
    int idx = blockIdx.x * 256 + threadIdx.x;
    if (idx >= 160000) return;
    int m = idx / 400, n = idx % 400;
    float r0 = (float)(n / 20 - m / 20) / 19.0f;
    float r1 = (float)(n % 20 - m % 20) / 19.0f;
    float o0 = B2[0], o1 = B2[1], o2 = B2[2], o3 = B2[3];
#pragma unroll
    for (int k = 0; k < 16; ++k) {
        float h = r0 * W1[k] + r1 * W1[16 + k] + B1[k];
        h = fmaxf(h, 0.0f);
        o0 += h * W2[k * 4 + 0];
        o1 += h * W2[k * 4 + 1];
        o2 += h * W2[k * 4 + 2];
        o3 += h * W2[k * 4 + 3];
    }
    size_t base = (size_t)m * 400 + n;
    biasT[base] = f2bf(o0);
    biasT[166400 + base] = f2bf(o1);
    biasT[2 * 166400 + base] = f2bf(o2);
    biasT[3 * 166400 + base] = f2bf(o3);
}

// ---------------- K2: fused qkv+grid conv1x1 as MFMA GEMM, shuffle on write ----------------
// Block = (b, H0, 32-pixel chunk). LDS x-tile bf16, XOR-swizzled. Wave w owns oc [w*64,(w+1)*64)
// = exactly one of Q/K/V/XG. mfma(W,X): C col = pixel, row = oc.
__global__ __launch_bounds__(256) void k_conv(
    const float* __restrict__ x, const ushort* __restrict__ Wc,
    const float* __restrict__ Bc,
    ushort* __restrict__ Qb, ushort* __restrict__ Kb,
    ushort* __restrict__ Vb, ushort* __restrict__ XGb)
{
    __shared__ __align__(16) ushort XL[32 * 64];
    int blk = blockIdx.x;                 // 1600 = 2*160*5
    int b = blk / 800, rem = blk % 800;
    int H0 = rem / 5, wt = rem % 5;
    int w0 = wt * 32;
    int tid = threadIdx.x;

    // stage: thread (c, q4) reads 8 consecutive pixels of channel c
    {
        int c = tid >> 2, q4 = tid & 3;
        const float* xr = x + ((size_t)(b * 64 + c) * 160 + H0) * 160 + w0 + q4 * 8;
        float4 f0 = *reinterpret_cast<const float4*>(xr);
        float4 f1 = *reinterpret_cast<const float4*>(xr + 4);
        char* base = reinterpret_cast<char*>(XL);
#pragma unroll
        for (int k = 0; k < 8; ++k) {
            float v = (k < 4) ? ((const float*)&f0)[k] : ((const float*)&f1)[k - 4];
            int p = q4 * 8 + k;
            int byt = p * 128 + ((2 * c) ^ ((p & 7) << 4));
            *reinterpret_cast<ushort*>(base + byt) = f2bf(v);
        }
    }

    int lane = tid & 63, w = tid >> 6;
    int l31 = lane & 31, hi = lane >> 5;

    bf16x8 wf[2][4];
#pragma unroll
    for (int nt = 0; nt < 2; ++nt)
#pragma unroll
        for (int kk = 0; kk < 4; ++kk)
            wf[nt][kk] = ld16(&Wc[(size_t)(w * 64 + nt * 32 + l31) * 64 + kk * 16 + hi * 8]);
    __syncthreads();

    f32x16 acc0 = 0.0f, acc1 = 0.0f;
    const char* base = reinterpret_cast<const char*>(XL);
#pragma unroll
    for (int kk = 0; kk < 4; ++kk) {
        int byt = l31 * 128 + (((kk * 32 + hi * 16)) ^ ((l31 & 7) << 4));
        bf16x8 xf;
        {
            union { uint4 q; bf16x8 v; } u;
            u.q = *reinterpret_cast<const uint4*>(base + byt);
            xf = u.v;
        }
        acc0 = __builtin_amdgcn_mfma_f32_32x32x16_bf16(wf[0][kk], xf, acc0, 0, 0, 0);
        acc1 = __builtin_amdgcn_mfma_f32_32x32x16_bf16(wf[1][kk], xf, acc1, 0, 0, 0);
    }

    // store: pixel = l31, token (bp,n) from shuffle; cc = oc&63
    int W0 = w0 + l31, ww = W0 >> 3, j = W0 & 7;
    int bp = b * 64 + (H0 & 7) * 8 + j;
    int n  = (H0 >> 3) * 20 + ww;
    ushort* outb = (w == 0) ? Qb : (w == 1) ? Kb : (w == 2) ? Vb : XGb;
    ushort* dst = outb + ((size_t)bp * NP + n) * 64;
#pragma unroll
    for (int nt = 0; nt < 2; ++nt) {
        const f32x16& a = nt ? acc1 : acc0;
#pragma unroll
        for (int g = 0; g < 4; ++g) {
            int cc = nt * 32 + 8 * g + 4 * hi;
            int oc = w * 64 + cc;
            uint2 uu;
            uu.x = pk2(a[4 * g + 0] + Bc[oc + 0], a[4 * g + 1] + Bc[oc + 1]);
            uu.y = pk2(a[4 * g + 2] + Bc[oc + 2], a[4 * g + 3] + Bc[oc + 3]);
            *reinterpret_cast<uint2*>(dst + cc) = uu;
        }
    }
}

// ---------------- K3: MFMA attention. One block per (bp, head); 4 waves ----------------
__global__ __launch_bounds__(256) void k_attn_mfma(
    const ushort* __restrict__ Qg, const ushort* __restrict__ Kg,
    const ushort* __restrict__ Vg, const ushort* __restrict__ biasT,
    ushort* __restrict__ O, float scale)
{
    __shared__ ushort Ks[NP * 16];    // [m][d]
    __shared__ ushort Vt[16 * 424];   // [d][m]
    int blk = blockIdx.x;
    int bp = blk >> 2, h = blk & 3;
    int tid = threadIdx.x;

    const ushort* Ksrc = Kg + (size_t)bp * NP * 64 + h * 16;
    for (int i = tid; i < NP * 2; i += 256) {
        int row = i >> 1, half = i & 1;
        *reinterpret_cast<uint4*>(&Ks[row * 16 + half * 8]) =
            *reinterpret_cast<const uint4*>(&Ksrc[(size_t)row * 64 + half * 8]);
    }
    const ushort* Vsrc = Vg + (size_t)bp * NP * 64 + h * 16;
    {
        int c = tid & 15, r0 = tid >> 4;
        for (int row = r0; row < N_TOK; row += 16)
            Vt[c * 424 + row] = Vsrc[(size_t)row * 64 + c];
    }
    __syncthreads();

    int lane = tid & 63, w = tid >> 6;
    int l31 = lane & 31, hi = lane >> 5;
    const ushort* bh = biasT + (size_t)h * 166400;

    for (int qt = w; qt < 13; qt += 4) {
        int qbase = qt * 32;
        bf16x8 qf = ld16(&Qg[((size_t)bp * NP + qbase + l31) * 64 + h * 16 + hi * 8]);
        f32x16 acc = 0.0f;
        float lrun = 0.0f;

#pragma unroll
        for (int mt = 0; mt < 13; ++mt) {
            const int mbase = mt * 32;
            bf16x8 kf = ld16(&Ks[(mbase + l31) * 16 + hi * 8]);
            f32x16 zero = 0.0f;
            f32x16 sv = __builtin_amdgcn_mfma_f32_32x32x16_bf16(kf, qf, zero, 0, 0, 0);

            const ushort* bptr = bh + (size_t)mbase * 400 + qbase + l31 + hi * 1600;
            const int nv = (mt == 12) ? 8 : 16;
            float p[16];
            float rs = 0.0f;
#pragma unroll
            for (int r = 0; r < 16; ++r) {
                if (r < nv) {
                    float b = bf2f(bptr[((r & 3) + 8 * (r >> 2)) * 400]);
                    p[r] = __expf(fmaf(sv[r], scale, b));
                    rs += p[r];
                }
            }
            lrun += rs;

            {
                uint c0 = pk2(p[0], p[1]), c1 = pk2(p[2], p[3]);
                uint c2 = pk2(p[4], p[5]), c3 = pk2(p[6], p[7]);
                asm("v_permlane32_swap_b32 %0, %1" : "+v"(c0), "+v"(c2));
                asm("v_permlane32_swap_b32 %0, %1" : "+v"(c1), "+v"(c3));
                union { uint u[4]; bf16x8 v; } A;
                A.u[0] = c0; A.u[1] = c1; A.u[2] = c2; A.u[3] = c3;
                bf16x8 vf = ld16(&Vt[(lane & 15) * 424 + mbase + hi * 8]);
                acc = __builtin_amdgcn_mfma_f32_32x32x16_bf16(A.v, vf, acc, 0, 0, 0);
            }
            if (mt < 12) {
                uint c4 = pk2(p[8], p[9]),  c5 = pk2(p[10], p[11]);
                uint c6 = pk2(p[12], p[13]), c7 = pk2(p[14], p[15]);
                asm("v_permlane32_swap_b32 %0, %1" : "+v"(c4), "+v"(c6));
                asm("v_permlane32_swap_b32 %0, %1" : "+v"(c5), "+v"(c7));
                union { uint u[4]; bf16x8 v; } A;
                A.u[0] = c4; A.u[1] = c5; A.u[2] = c6; A.u[3] = c7;
                bf16x8 vf = ld16(&Vt[(lane & 15) * 424 + mbase + 16 + hi * 8]);
                acc = __builtin_amdgcn_mfma_f32_32x32x16_bf16(A.v, vf, acc, 0, 0, 0);
            }
        }

        float tot = lrun + __shfl_xor(lrun, 32);
        float inv = 1.0f / tot;
        int dd = l31;
#pragma unroll
        for (int r = 0; r < 16; ++r) {
            int moff = (r & 3) + 8 * (r >> 2) + 4 * hi;
            int q = qbase + moff;
            float iv = __shfl(inv, moff);
            if (dd < 16 && q < N_TOK)
                O[((size_t)bp * N_TOK + q) * 64 + h * 16 + dd] = f2bf(acc[r] * iv);
        }
    }
}

// ---------------- K4: 64x64 proj as MFMA GEMM ----------------
// In bf16 token-major [51200][64]; OUT_BF16: out bf16 NP-padded; else fp32 [51200][64].
template<int OUT_BF16>
__global__ __launch_bounds__(256) void k_proj(
    const ushort* __restrict__ In, const ushort* __restrict__ Wp,
    const float* __restrict__ Bv, void* __restrict__ Out)
{
    __shared__ __align__(16) ushort XL[128 * 64];
    size_t t0 = (size_t)blockIdx.x * 128;
    int tid = threadIdx.x;

    char* basec = reinterpret_cast<char*>(XL);
#pragma unroll
    for (int it = 0; it < 4; ++it) {
        int idx = tid + it * 256;
        int p = idx >> 3, c8 = idx & 7;
        uint4 v = *reinterpret_cast<const uint4*>(In + (t0 + p) * 64 + c8 * 8);
        int byt = p * 128 + ((c8 * 16) ^ ((p & 7) << 4));
        *reinterpret_cast<uint4*>(basec + byt) = v;
    }

    int lane = tid & 63, w = tid >> 6;
    int l31 = lane & 31, hi = lane >> 5;

    bf16x8 wf[2][4];
#pragma unroll
    for (int nt = 0; nt < 2; ++nt)
#pragma unroll
        for (int kk = 0; kk < 4; ++kk)
            wf[nt][kk] = ld16(&Wp[(size_t)(nt * 32 + l31) * 64 + kk * 16 + hi * 8]);
    __syncthreads();

    int prow = w * 32 + l31;
    f32x16 acc0 = 0.0f, acc1 = 0.0f;
#pragma unroll
    for (int kk = 0; kk < 4; ++kk) {
        int byt = prow * 128 + (((kk * 32 + hi * 16)) ^ ((prow & 7) << 4));
        union { uint4 q; bf16x8 v; } u;
        u.q = *reinterpret_cast<const uint4*>(basec + byt);
        acc0 = __builtin_amdgcn_mfma_f32_32x32x16_bf16(wf[0][kk], u.v, acc0, 0, 0, 0);
        acc1 = __builtin_amdgcn_mfma_f32_32x32x16_bf16(wf[1][kk], u.v, acc1, 0, 0, 0);
    }

    size_t t = t0 + prow;
    if (OUT_BF16) {
        int bp = (int)(t / 400), n = (int)(t % 400);
        ushort* dst = reinterpret_cast<ushort*>(Out) + ((size_t)bp * NP + n) * 64;
#pragma unroll
        for (int nt = 0; nt < 2; ++nt) {
            const f32x16& a = nt ? acc1 : acc0;
#pragma unroll
            for (int g = 0; g < 4; ++g) {
                int cc = nt * 32 + 8 * g + 4 * hi;
                uint2 uu;
                uu.x = pk2(a[4 * g + 0] + Bv[cc + 0], a[4 * g + 1] + Bv[cc + 1]);
                uu.y = pk2(a[4 * g + 2] + Bv[cc + 2], a[4 * g + 3] + Bv[cc + 3]);
                *reinterpret_cast<uint2*>(dst + cc) = uu;
            }
        }
    } else {
        float* dst = reinterpret_cast<float*>(Out) + t * 64;
#pragma unroll
        for (int nt = 0; nt < 2; ++nt) {
            const f32x16& a = nt ? acc1 : acc0;
#pragma unroll
            for (int g = 0; g < 4; ++g) {
                int cc = nt * 32 + 8 * g + 4 * hi;
                float4 f;
                f.x = a[4 * g + 0] + Bv[cc + 0];
                f.y = a[4 * g + 1] + Bv[cc + 1];
                f.z = a[4 * g + 2] + Bv[cc + 2];
                f.w = a[4 * g + 3] + Bv[cc + 3];
                *reinterpret_cast<float4*>(dst + cc) = f;
            }
        }
    }
}

// ---------------- K5: grid_unshuffle (token-major fp32 -> [B][C][160][160]) ----------------
__global__ __launch_bounds__(256) void k_unshuffle(
    const float* __restrict__ In, float* __restrict__ out)
{
    __shared__ __align__(16) float il[160 * 64];
    int blk = blockIdx.x;
    int b = blk / 160, rem = blk % 160, iI = rem / 20, hh = rem % 20;
    int tid = threadIdx.x;

    for (int idx = tid; idx < 2560; idx += 256) {
        int j = idx / 320, r2 = idx % 320, ww = r2 / 16, c4 = r2 % 16;
        int bp = b * 64 + iI * 8 + j;
        int n  = hh * 20 + ww;
        float4 v = reinterpret_cast<const float4*>(In + ((size_t)bp * 400 + n) * 64)[c4];
        reinterpret_cast<float4*>(&il[(ww * 8 + j) * 64])[c4] = v;
    }
    __syncthreads();

    int c = tid >> 2, q = tid & 3;
    int H0 = hh * 8 + iI;
    float* og = out + ((size_t)(b * 64 + c) * 160 + H0) * 160;
#pragma unroll
    for (int k = 0; k < 10; ++k) {
        int f = q + 4 * k;
        float4 v;
        v.x = il[(4 * f + 0) * 64 + c];
        v.y = il[(4 * f + 1) * 64 + c];
        v.z = il[(4 * f + 2) * 64 + c];
        v.w = il[(4 * f + 3) * 64 + c];
        reinterpret_cast<float4*>(og)[f] = v;
    }
}

extern "C" void kernel_launch(void* const* d_in, const int* in_sizes, int n_in,
                              void* d_out, int out_size, void* d_ws, size_t ws_size,
                              hipStream_t stream)
{
    const float* x      = (const float*)d_in[0];
    const float* qkv_w  = (const float*)d_in[1];
    const float* qkv_b  = (const float*)d_in[2];
    const float* grid_w = (const float*)d_in[3];
    const float* grid_b = (const float*)d_in[4];
    const float* pw1    = (const float*)d_in[5];
    const float* pb1    = (const float*)d_in[6];
    const float* pw2    = (const float*)d_in[7];
    const float* pb2    = (const float*)d_in[8];
    const float* p1w    = (const float*)d_in[9];
    const float* p1b    = (const float*)d_in[10];
    const float* p2w    = (const float*)d_in[11];
    const float* p2b    = (const float*)d_in[12];

    // workspace layout (byte offsets, all 16B-aligned)
    char* W = (char*)d_ws;
    ushort* biasT = (ushort*)(W + 0);            // 4*416*400*2   = 1,331,200
    ushort* Wc    = (ushort*)(W + 1331200);      // 256*64*2      =    32,768
    ushort* Wp1   = (ushort*)(W + 1363968);      // 64*64*2       =     8,192
    ushort* Wp2   = (ushort*)(W + 1372160);      //                     8,192
    float*  Bc    = (float*) (W + 1380352);      // 256*4         =     1,024
    const size_t BB = (size_t)BP * NP * 64 * 2;  // 6,815,744 per bf16 NP buffer
    ushort* Qb = (ushort*)(W + 1381376);
    ushort* Kb = (ushort*)(W + 1381376 + 1 * BB);
    ushort* Vb = (ushort*)(W + 1381376 + 2 * BB);
    ushort* XG = (ushort*)(W + 1381376 + 3 * BB);
    ushort* P1 = (ushort*)(W + 1381376 + 4 * BB);
    const size_t OB = (size_t)BP * N_TOK * 64 * 2;  // 6,553,600 per bf16 O buffer
    ushort* O1 = (ushort*)(W + 1381376 + 5 * BB);
    ushort* O2 = (ushort*)(W + 1381376 + 5 * BB + OB);
    float*  OF = (float*) (W + 1381376 + 5 * BB + 2 * OB);  // fp32 13,107,200
    float*  out = (float*)d_out;

    k_prepw<<<97, 256, 0, stream>>>(qkv_w, qkv_b, grid_w, grid_b, p1w, p2w, Wc, Bc, Wp1, Wp2);
    k_biasT<<<625, 256, 0, stream>>>(pw1, pb1, pw2, pb2, biasT);
    k_conv<<<1600, 256, 0, stream>>>(x, Wc, Bc, Qb, Kb, Vb, XG);
    // attn1: q=XG, k=Kb, v=Vb -> O1 (bf16); proj1 -> P1 (bf16, NP-padded)
    k_attn_mfma<<<512, 256, 0, stream>>>(XG, Kb, Vb, biasT, O1, 0.25f);
    k_proj<1><<<400, 256, 0, stream>>>(O1, Wp1, p1b, (void*)P1);
    // attn2: q=Qb, k=XG, v=P1 -> O2 (bf16); proj2 -> OF (fp32)
    k_attn_mfma<<<512, 256, 0, stream>>>(Qb, XG, P1, biasT, O2, 0.25f);
    k_proj<0><<<400, 256, 0, stream>>>(O2, Wp2, p2b, (void*)OF);
    k_unshuffle<<<320, 256, 0, stream>>>(OF, out);
}